// Round 2
// baseline (177.484 us; speedup 1.0000x reference)
//
#include <hip/hip_runtime.h>

// StructuralAttention v2: algebraic fusion.
//   S_eff = X*(Wq^T Wk/sqrt(d))*X^T + 1*v^T   (row-constant terms cancel in softmax)
//   v     = X*(Wk^T bq)/sqrt(d)
//   O     = (P*X)*Wv^T / rowsum(P) + bv        (V never materialized)
// Precompute kernel: Mt[b][a] = sum_o Wq[o][a]Wk[o][b] * scale (bf16, pre-swizzled), w (f32).
// Main kernel: 1 block (512 thr, 8 waves) per graph, LDS 65 KB -> 2 blocks/CU.
// Hot MFMAs are 16x16x32 bf16; X^T fragments for the PV step and the final
// T^T fragments are produced by identity-MFMA transposes (no strided LDS access).

typedef float f32x4 __attribute__((ext_vector_type(4)));
typedef unsigned int u32x2 __attribute__((ext_vector_type(2)));
typedef unsigned int u32x4 __attribute__((ext_vector_type(4)));
typedef short s16x4 __attribute__((ext_vector_type(4)));
typedef short s16x8 __attribute__((ext_vector_type(8)));

#define SCALE 0.088388347648318447f  // 1/sqrt(128)
#define VOFF  65536                  // v vector (f32[256]) after Xs
#define LDSSZ 66560

__device__ __forceinline__ unsigned bf16pk(float a, float b) {
    unsigned ua = __builtin_bit_cast(unsigned, a);
    unsigned ub = __builtin_bit_cast(unsigned, b);
    ua += 0x7fffu + ((ua >> 16) & 1u);   // RNE
    ub += 0x7fffu + ((ub >> 16) & 1u);
    return (ua >> 16) | (ub & 0xffff0000u);
}
__device__ __forceinline__ unsigned short bf16s(float a) {
    unsigned ua = __builtin_bit_cast(unsigned, a);
    ua += 0x7fffu + ((ua >> 16) & 1u);
    return (unsigned short)(ua >> 16);
}
__device__ __forceinline__ f32x4 mfma16(u32x2 a, u32x2 b, f32x4 c) {
    return __builtin_amdgcn_mfma_f32_16x16x16bf16_1k(
        __builtin_bit_cast(s16x4, a), __builtin_bit_cast(s16x4, b), c, 0, 0, 0);
}
__device__ __forceinline__ f32x4 mfma32(u32x4 a, u32x4 b, f32x4 c) {
    return __builtin_amdgcn_mfma_f32_16x16x32_bf16(
        __builtin_bit_cast(s16x8, a), __builtin_bit_cast(s16x8, b), c, 0, 0, 0);
}

// Xs: bf16[256][128], row-major, XOR swizzle spreading d-bits with row
__device__ __forceinline__ int ks_off(int row, int d) {
    return (row << 8) + (((d << 1)) ^ ((row & 15) << 3));
}
// Mt / Wv staging: bf16[128][128], 16B-safe swizzle
__device__ __forceinline__ int wf4_off(int j, int d) {
    return (j << 8) + (((d << 1)) ^ ((j & 15) << 4));
}

// ---------------- precompute: Mt (bf16, swizzled) + w (f32) -> d_ws ----------------
extern "C" __global__ void __launch_bounds__(256)
sattn_pre(const float* __restrict__ Wq, const float* __restrict__ bq,
          const float* __restrict__ Wk, char* __restrict__ wsb)
{
    const int b = blockIdx.x, t = threadIdx.x;
    if (b < 64) {
        const int row = b * 2 + (t >> 7);   // 0..127 (Mt row index = "b" feature)
        const int a   = t & 127;
        float acc = 0.f;
#pragma unroll 4
        for (int o = 0; o < 128; ++o)
            acc += Wq[o * 128 + a] * Wk[o * 128 + row];
        *(unsigned short*)(wsb + wf4_off(row, a)) = bf16s(acc * SCALE);
    } else if (t < 128) {
        float acc = 0.f;
#pragma unroll 4
        for (int o = 0; o < 128; ++o)
            acc += bq[o] * Wk[o * 128 + t];
        *(float*)(wsb + 32768 + 4 * t) = acc * SCALE;
    }
}

// ---------------- main fused kernel: 1 block per graph ----------------
extern "C" __global__ void __launch_bounds__(512, 4)
sattn(const float* __restrict__ x, const float* __restrict__ Wv,
      const float* __restrict__ bv, const char* __restrict__ wsb,
      float* __restrict__ out)
{
    extern __shared__ char sm[];
    const int t    = threadIdx.x;
    const int lane = t & 63;
    const int w    = t >> 6;
    const int h    = lane & 15;
    const int g    = lane >> 4;
    const int R0   = blockIdx.x << 8;
    const int wr0  = w << 5;
    const f32x4 Z  = {0.f, 0.f, 0.f, 0.f};

    // -- phase 0: linear copy of pre-swizzled Mt (32 KB) into LDS[0,32K) --
    {
        const u32x4* src = (const u32x4*)wsb;
        u32x4* dst = (u32x4*)sm;
#pragma unroll
        for (int i = 0; i < 4; ++i) dst[t + 512 * i] = src[t + 512 * i];
    }

    // -- X load (fp32 -> bf16 frags) + v = X*w accumulation --
    u32x2 xf[2][8];
    float vp0 = 0.f, vp1 = 0.f;
    const float* wvec = (const float*)(wsb + 32768);
#pragma unroll
    for (int rt = 0; rt < 2; ++rt) {
        const float* xr = x + (size_t)(R0 + wr0 + 16 * rt + h) * 128 + 4 * g;
        float vacc = 0.f;
#pragma unroll
        for (int c = 0; c < 8; ++c) {
            f32x4 v = *(const f32x4*)(xr + 16 * c);
            f32x4 wc = *(const f32x4*)(wvec + 16 * c + 4 * g);
            vacc += v.x * wc.x + v.y * wc.y + v.z * wc.z + v.w * wc.w;
            xf[rt][c] = (u32x2){ bf16pk(v.x, v.y), bf16pk(v.z, v.w) };
        }
        if (rt == 0) vp0 = vacc; else vp1 = vacc;
    }
    vp0 += __shfl_xor(vp0, 16); vp0 += __shfl_xor(vp0, 32);
    vp1 += __shfl_xor(vp1, 16); vp1 += __shfl_xor(vp1, 32);
    if (g == 0) {
        *(float*)(sm + VOFF + (wr0 + h) * 4)      = vp0;
        *(float*)(sm + VOFF + (wr0 + 16 + h) * 4) = vp1;
    }
    __syncthreads();   // Mt + v visible

    // -- Y^T = Mt * X^T  (yf[jt][rt] = B-operand-ready Y^T fragments) --
    u32x2 yf[8][2];
#pragma unroll
    for (int jt = 0; jt < 8; ++jt) {
        f32x4 a0 = Z, a1 = Z;
#pragma unroll
        for (int c2 = 0; c2 < 4; ++c2) {
            u32x2 mlo = *(const u32x2*)(sm + wf4_off(h + 16 * jt, 32 * c2 + 4 * g));
            u32x2 mhi = *(const u32x2*)(sm + wf4_off(h + 16 * jt, 32 * c2 + 16 + 4 * g));
            u32x4 A = (u32x4){ mlo.x, mlo.y, mhi.x, mhi.y };
            u32x4 B0 = (u32x4){ xf[0][2 * c2].x, xf[0][2 * c2].y, xf[0][2 * c2 + 1].x, xf[0][2 * c2 + 1].y };
            u32x4 B1 = (u32x4){ xf[1][2 * c2].x, xf[1][2 * c2].y, xf[1][2 * c2 + 1].x, xf[1][2 * c2 + 1].y };
            a0 = mfma32(A, B0, a0);
            a1 = mfma32(A, B1, a1);
        }
        yf[jt][0] = (u32x2){ bf16pk(a0.x, a0.y), bf16pk(a0.z, a0.w) };
        yf[jt][1] = (u32x2){ bf16pk(a1.x, a1.y), bf16pk(a1.z, a1.w) };
    }
    __syncthreads();   // all waves done reading Mt

    // -- write Xs (bf16 [256][128], swizzled) from register frags --
#pragma unroll
    for (int rt = 0; rt < 2; ++rt)
#pragma unroll
        for (int c = 0; c < 8; ++c)
            *(u32x2*)(sm + ks_off(wr0 + 16 * rt + h, 16 * c + 4 * g)) = xf[rt][c];
    __syncthreads();

    // identity B-fragment for transpose-MFMAs: B[k=4g+j][col=h] = (4g+j==h)
    const int ii = h - 4 * g;
    u32x2 idf;
    idf.x = (ii == 0 ? 0x3F80u : 0u) | (ii == 1 ? (0x3F80u << 16) : 0u);
    idf.y = (ii == 2 ? 0x3F80u : 0u) | (ii == 3 ? (0x3F80u << 16) : 0u);

    // -- attention main loop: S = Y*X^T + v ; P = exp(S); T += P*X --
    f32x4 Tacc[8][2];
#pragma unroll
    for (int jt = 0; jt < 8; ++jt) { Tacc[jt][0] = Z; Tacc[jt][1] = Z; }
    float ls0 = 0.f, ls1 = 0.f;

#pragma unroll 2
    for (int kc2 = 0; kc2 < 8; ++kc2) {
        u32x2 pe[2][2];
#pragma unroll
        for (int kk = 0; kk < 2; ++kk) {
            const int kc = 2 * kc2 + kk;
            f32x4 a0 = Z, a1 = Z;
#pragma unroll
            for (int c2 = 0; c2 < 4; ++c2) {
                u32x2 xlo = *(const u32x2*)(sm + ks_off(16 * kc + h, 32 * c2 + 4 * g));
                u32x2 xhi = *(const u32x2*)(sm + ks_off(16 * kc + h, 32 * c2 + 16 + 4 * g));
                u32x4 A = (u32x4){ xlo.x, xlo.y, xhi.x, xhi.y };
                u32x4 B0 = (u32x4){ yf[2 * c2][0].x, yf[2 * c2][0].y, yf[2 * c2 + 1][0].x, yf[2 * c2 + 1][0].y };
                u32x4 B1 = (u32x4){ yf[2 * c2][1].x, yf[2 * c2][1].y, yf[2 * c2 + 1][1].x, yf[2 * c2 + 1][1].y };
                a0 = mfma32(A, B0, a0);
                a1 = mfma32(A, B1, a1);
            }
            f32x4 vv = *(const f32x4*)(sm + VOFF + (16 * kc + 4 * g) * 4);
            float e0[4], e1[4];
#pragma unroll
            for (int r = 0; r < 4; ++r) {
                e0[r] = __expf(a0[r] + vv[r]);
                e1[r] = __expf(a1[r] + vv[r]);
            }
            ls0 += e0[0] + e0[1] + e0[2] + e0[3];
            ls1 += e1[0] + e1[1] + e1[2] + e1[3];
            pe[kk][0] = (u32x2){ bf16pk(e0[0], e0[1]), bf16pk(e0[2], e0[3]) };
            pe[kk][1] = (u32x2){ bf16pk(e1[0], e1[1]), bf16pk(e1[2], e1[3]) };
        }
        u32x4 pa0 = (u32x4){ pe[0][0].x, pe[0][0].y, pe[1][0].x, pe[1][0].y };
        u32x4 pa1 = (u32x4){ pe[0][1].x, pe[0][1].y, pe[1][1].x, pe[1][1].y };
#pragma unroll
        for (int jt = 0; jt < 8; ++jt) {
            // X^T fragments via identity-MFMA transpose of row-major Xs reads
            u32x2 ra = *(const u32x2*)(sm + ks_off(16 * (2 * kc2) + h,     16 * jt + 4 * g));
            u32x2 rb = *(const u32x2*)(sm + ks_off(16 * (2 * kc2 + 1) + h, 16 * jt + 4 * g));
            f32x4 ta = mfma16(ra, idf, Z);   // lane: X[32kc2+4g+r][16jt+h]
            f32x4 tb = mfma16(rb, idf, Z);
            u32x4 tB = (u32x4){ bf16pk(ta.x, ta.y), bf16pk(ta.z, ta.w),
                                bf16pk(tb.x, tb.y), bf16pk(tb.z, tb.w) };
            Tacc[jt][0] = mfma32(pa0, tB, Tacc[jt][0]);
            Tacc[jt][1] = mfma32(pa1, tB, Tacc[jt][1]);
        }
    }
    __syncthreads();   // all Xs reads done; [0,32K) reusable

    // -- stage Wv into LDS[0,32K) (fp32 -> bf16, swizzled) --
    {
        const int j  = t >> 2;
        const int d0 = (t & 3) << 5;
        const float* src = Wv + j * 128 + d0;
#pragma unroll
        for (int m2 = 0; m2 < 4; ++m2) {
            f32x4 a = *(const f32x4*)(src + 8 * m2);
            f32x4 b = *(const f32x4*)(src + 8 * m2 + 4);
            u32x4 p = (u32x4){ bf16pk(a.x, a.y), bf16pk(a.z, a.w),
                               bf16pk(b.x, b.y), bf16pk(b.z, b.w) };
            *(u32x4*)(sm + wf4_off(j, d0 + 8 * m2)) = p;
        }
    }

    // (register-only while Wv staging lands) ls reduce + transpose T -> B-frags
    ls0 += __shfl_xor(ls0, 16); ls0 += __shfl_xor(ls0, 32);
    ls1 += __shfl_xor(ls1, 16); ls1 += __shfl_xor(ls1, 32);
    const float li0 = 1.0f / ls0;   // for q = wr0 + h
    const float li1 = 1.0f / ls1;   // for q = wr0 + 16 + h

    u32x4 tBO[4][2];
#pragma unroll
    for (int c2 = 0; c2 < 4; ++c2) {
#pragma unroll
        for (int qt = 0; qt < 2; ++qt) {
            f32x4 A0 = (qt == 0) ? Tacc[2 * c2][0]     : Tacc[2 * c2][1];
            f32x4 A1 = (qt == 0) ? Tacc[2 * c2 + 1][0] : Tacc[2 * c2 + 1][1];
            u32x2 p0 = (u32x2){ bf16pk(A0.x, A0.y), bf16pk(A0.z, A0.w) };
            u32x2 p1 = (u32x2){ bf16pk(A1.x, A1.y), bf16pk(A1.z, A1.w) };
            f32x4 d0 = mfma16(p0, idf, Z);   // lane: T[q=h][d=32c2+4g+r]
            f32x4 d1 = mfma16(p1, idf, Z);   // lane: T[q=h][d=32c2+16+4g+r]
            tBO[c2][qt] = (u32x4){ bf16pk(d0.x, d0.y), bf16pk(d0.z, d0.w),
                                   bf16pk(d1.x, d1.y), bf16pk(d1.z, d1.w) };
        }
    }
    __syncthreads();   // Wv staged

    // -- O^T = Wv * T^T ; normalize + bias ; coalesced f32x4 stores --
#pragma unroll
    for (int ot = 0; ot < 8; ++ot) {
        f32x4 o0 = Z, o1 = Z;
#pragma unroll
        for (int c2 = 0; c2 < 4; ++c2) {
            u32x2 wlo = *(const u32x2*)(sm + wf4_off(h + 16 * ot, 32 * c2 + 4 * g));
            u32x2 whi = *(const u32x2*)(sm + wf4_off(h + 16 * ot, 32 * c2 + 16 + 4 * g));
            u32x4 A = (u32x4){ wlo.x, wlo.y, whi.x, whi.y };
            o0 = mfma32(A, tBO[c2][0], o0);
            o1 = mfma32(A, tBO[c2][1], o1);
        }
        f32x4 bvv = *(const f32x4*)(bv + 16 * ot + 4 * g);
        f32x4 r0v, r1v;
#pragma unroll
        for (int r = 0; r < 4; ++r) {
            r0v[r] = o0[r] * li0 + bvv[r];
            r1v[r] = o1[r] * li1 + bvv[r];
        }
        *(f32x4*)(out + (size_t)(R0 + wr0 + h) * 128 + 16 * ot + 4 * g)      = r0v;
        *(f32x4*)(out + (size_t)(R0 + wr0 + 16 + h) * 128 + 16 * ot + 4 * g) = r1v;
    }
}

extern "C" void kernel_launch(void* const* d_in, const int* in_sizes, int n_in,
                              void* d_out, int out_size, void* d_ws, size_t ws_size,
                              hipStream_t stream) {
    const float* x  = (const float*)d_in[0];
    const float* Wq = (const float*)d_in[2];
    const float* bq = (const float*)d_in[3];
    const float* Wk = (const float*)d_in[4];
    const float* Wv = (const float*)d_in[6];
    const float* bv = (const float*)d_in[7];
    float* out = (float*)d_out;
    char* wsb = (char*)d_ws;

    hipFuncSetAttribute((const void*)sattn,
                        hipFuncAttributeMaxDynamicSharedMemorySize, LDSSZ);

    sattn_pre<<<dim3(65), dim3(256), 0, stream>>>(Wq, bq, Wk, wsb);
    sattn<<<dim3(512), dim3(512), LDSSZ, stream>>>(x, Wv, bv, wsb, out);
}

// Round 3
// 110.483 us; speedup vs baseline: 1.6064x; 1.6064x over previous
//
#include <hip/hip_runtime.h>
#include <hip/hip_bf16.h>

// StructuralAttention v3: algebraic fusion, register-budgeted.
//   S_eff = X*M*X^T + 1*v^T,  M = Wq^T Wk / sqrt(d)   (row-const terms cancel in softmax)
//   v     = X*(Wk^T bq)/sqrt(d)
//   O     = (P*X)*Wv^T / rowsum(P) + bv               (K,V never materialized)
// Pre-kernel: Mt bf16[128][128] row-major + w f32[128] -> d_ws.
// Main: 1 block (512 thr, 8 waves) per graph. LDS 65K = Xs bf16[256][128] + v f32[256]
// -> 2 blocks/CU. Main loop is q-outer 2-pass so live regs stay under the 128 cap
// (v2 spilled 390 MB of scratch at this cap with the q-both structure).
// Mt is read straight from global (L2-resident, shared by all blocks).

typedef float f32x4 __attribute__((ext_vector_type(4)));
typedef unsigned int u32x2 __attribute__((ext_vector_type(2)));
typedef unsigned int u32x4 __attribute__((ext_vector_type(4)));
typedef short s16x4 __attribute__((ext_vector_type(4)));
typedef short s16x8 __attribute__((ext_vector_type(8)));

#define SCALE 0.088388347648318447f  // 1/sqrt(128)
#define VOFF  65536                  // v f32[256] after Xs
#define LDSSZ 66560

__device__ __forceinline__ unsigned short bf16s(float a) {
    return __builtin_bit_cast(unsigned short, __float2bfloat16(a));  // RNE, fuses to v_cvt_pk
}
__device__ __forceinline__ unsigned bf16pk(float a, float b) {
    return (unsigned)bf16s(a) | ((unsigned)bf16s(b) << 16);
}
__device__ __forceinline__ f32x4 mfma16(u32x2 a, u32x2 b, f32x4 c) {
    return __builtin_amdgcn_mfma_f32_16x16x16bf16_1k(
        __builtin_bit_cast(s16x4, a), __builtin_bit_cast(s16x4, b), c, 0, 0, 0);
}
__device__ __forceinline__ f32x4 mfma32(u32x4 a, u32x4 b, f32x4 c) {
    return __builtin_amdgcn_mfma_f32_16x16x32_bf16(
        __builtin_bit_cast(s16x8, a), __builtin_bit_cast(s16x8, b), c, 0, 0, 0);
}

// Xs: bf16[256][128] row-major + XOR swizzle (optimal 4-lane/8B-slot spread)
__device__ __forceinline__ int ks_off(int row, int d) {
    return (row << 8) + (((d << 1)) ^ ((row & 15) << 3));
}
// Wv staging: bf16[128][128], 16B-write-safe swizzle
__device__ __forceinline__ int wf4_off(int j, int d) {
    return (j << 8) + (((d << 1)) ^ ((j & 15) << 4));
}

// ---------------- precompute: Mt bf16 row-major + w f32 -> d_ws ----------------
extern "C" __global__ void __launch_bounds__(256)
sattn_pre(const float* __restrict__ Wq, const float* __restrict__ bq,
          const float* __restrict__ Wk, char* __restrict__ wsb)
{
    const int b = blockIdx.x, t = threadIdx.x;
    if (b < 64) {
        const int row = b * 2 + (t >> 7);   // Mt row = "k-side" feature b
        const int a   = t & 127;
        float acc = 0.f;
#pragma unroll 4
        for (int o = 0; o < 128; ++o)
            acc += Wq[o * 128 + a] * Wk[o * 128 + row];
        *(unsigned short*)(wsb + (row << 8) + (a << 1)) = bf16s(acc * SCALE);
    } else if (t < 128) {
        float acc = 0.f;
#pragma unroll 4
        for (int o = 0; o < 128; ++o)
            acc += bq[o] * Wk[o * 128 + t];
        *(float*)(wsb + 32768 + 4 * t) = acc * SCALE;
    }
}

// ---------------- main fused kernel: 1 block per graph ----------------
extern "C" __global__ void __launch_bounds__(512, 4)
sattn(const float* __restrict__ x, const float* __restrict__ Wv,
      const float* __restrict__ bv, const char* __restrict__ wsb,
      float* __restrict__ out)
{
    extern __shared__ char sm[];
    const int t    = threadIdx.x;
    const int lane = t & 63;
    const int w    = t >> 6;
    const int h    = lane & 15;
    const int g    = lane >> 4;
    const int R0   = blockIdx.x << 8;
    const int wr0  = w << 5;
    const f32x4 Z  = {0.f, 0.f, 0.f, 0.f};

    // -- phase A: load X rows (fp32 -> bf16 frags) + v = X*w partial --
    u32x2 xf[2][8];
    float vp0 = 0.f, vp1 = 0.f;
    const float* wvec = (const float*)(wsb + 32768);
#pragma unroll
    for (int rt = 0; rt < 2; ++rt) {
        const float* xr = x + (size_t)(R0 + wr0 + 16 * rt + h) * 128 + 4 * g;
        float vacc = 0.f;
#pragma unroll
        for (int c = 0; c < 8; ++c) {
            f32x4 v = *(const f32x4*)(xr + 16 * c);
            f32x4 wc = *(const f32x4*)(wvec + 16 * c + 4 * g);
            vacc += v.x * wc.x + v.y * wc.y + v.z * wc.z + v.w * wc.w;
            xf[rt][c] = (u32x2){ bf16pk(v.x, v.y), bf16pk(v.z, v.w) };
        }
        if (rt == 0) vp0 = vacc; else vp1 = vacc;
    }
    vp0 += __shfl_xor(vp0, 16); vp0 += __shfl_xor(vp0, 32);
    vp1 += __shfl_xor(vp1, 16); vp1 += __shfl_xor(vp1, 32);
    if (g == 0) {
        *(float*)(sm + VOFF + (wr0 + h) * 4)      = vp0;
        *(float*)(sm + VOFF + (wr0 + 16 + h) * 4) = vp1;
    }

    // -- Y^T = Mt * X^T, Mt fragments straight from global (L2-resident) --
    u32x2 yf[8][2];   // yf[jt][qt]: lane holds Y[q=h][16jt+4g+r] for q-tile qt
#pragma unroll
    for (int jt = 0; jt < 8; ++jt) {
        f32x4 a0 = Z, a1 = Z;
#pragma unroll
        for (int c2 = 0; c2 < 4; ++c2) {
            const char* mp = wsb + ((h + 16 * jt) << 8) + ((32 * c2 + 4 * g) << 1);
            u32x2 mlo = *(const u32x2*)mp;
            u32x2 mhi = *(const u32x2*)(mp + 32);
            u32x4 A = (u32x4){ mlo.x, mlo.y, mhi.x, mhi.y };
            u32x4 B0 = (u32x4){ xf[0][2 * c2].x, xf[0][2 * c2].y, xf[0][2 * c2 + 1].x, xf[0][2 * c2 + 1].y };
            u32x4 B1 = (u32x4){ xf[1][2 * c2].x, xf[1][2 * c2].y, xf[1][2 * c2 + 1].x, xf[1][2 * c2 + 1].y };
            a0 = mfma32(A, B0, a0);
            a1 = mfma32(A, B1, a1);
        }
        yf[jt][0] = (u32x2){ bf16pk(a0.x, a0.y), bf16pk(a0.z, a0.w) };
        yf[jt][1] = (u32x2){ bf16pk(a1.x, a1.y), bf16pk(a1.z, a1.w) };
    }

    // -- write Xs (xf dead after this) --
#pragma unroll
    for (int rt = 0; rt < 2; ++rt)
#pragma unroll
        for (int c = 0; c < 8; ++c)
            *(u32x2*)(sm + ks_off(wr0 + 16 * rt + h, 16 * c + 4 * g)) = xf[rt][c];
    __syncthreads();   // Xs + v visible

    // identity B-fragment for transpose-MFMAs: B[k=4g+j][col=h] = (4g+j==h)
    const int ii = h - 4 * g;
    u32x2 idf;
    idf.x = (ii == 0 ? 0x3F80u : 0u) | (ii == 1 ? (0x3F80u << 16) : 0u);
    idf.y = (ii == 2 ? 0x3F80u : 0u) | (ii == 3 ? (0x3F80u << 16) : 0u);

    // -- main loop, q-outer: per pass 16 q-rows/wave; Tacc[8] (32 regs) live --
    u32x4 tBO[2][4];   // packed T^T B-fragments per q-tile
    float li[2];
#pragma unroll
    for (int qt = 0; qt < 2; ++qt) {
        f32x4 Tacc[8];
#pragma unroll
        for (int jt = 0; jt < 8; ++jt) Tacc[jt] = Z;
        float ls = 0.f;

#pragma unroll 1
        for (int kc2 = 0; kc2 < 8; ++kc2) {
            u32x2 pk2[2];
#pragma unroll
            for (int kk = 0; kk < 2; ++kk) {
                const int kc = 2 * kc2 + kk;
                f32x4 a0 = Z;
#pragma unroll
                for (int c2 = 0; c2 < 4; ++c2) {
                    u32x2 xlo = *(const u32x2*)(sm + ks_off(16 * kc + h, 32 * c2 + 4 * g));
                    u32x2 xhi = *(const u32x2*)(sm + ks_off(16 * kc + h, 32 * c2 + 16 + 4 * g));
                    u32x4 A = (u32x4){ xlo.x, xlo.y, xhi.x, xhi.y };
                    u32x4 B = (u32x4){ yf[2 * c2][qt].x, yf[2 * c2][qt].y,
                                       yf[2 * c2 + 1][qt].x, yf[2 * c2 + 1][qt].y };
                    a0 = mfma32(A, B, a0);
                }
                f32x4 vv = *(const f32x4*)(sm + VOFF + (16 * kc + 4 * g) * 4);
                float e0 = __expf(a0.x + vv.x), e1 = __expf(a0.y + vv.y);
                float e2 = __expf(a0.z + vv.z), e3 = __expf(a0.w + vv.w);
                ls += e0 + e1 + e2 + e3;
                pk2[kk] = (u32x2){ bf16pk(e0, e1), bf16pk(e2, e3) };
            }
            u32x4 pa = (u32x4){ pk2[0].x, pk2[0].y, pk2[1].x, pk2[1].y };
#pragma unroll
            for (int jt = 0; jt < 8; ++jt) {
                // X^T fragments via identity-MFMA transpose of row-major Xs reads
                u32x2 ra = *(const u32x2*)(sm + ks_off(32 * kc2 + h,      16 * jt + 4 * g));
                u32x2 rb = *(const u32x2*)(sm + ks_off(32 * kc2 + 16 + h, 16 * jt + 4 * g));
                f32x4 ta = mfma16(ra, idf, Z);   // lane: X[32kc2+4g+r][16jt+h]
                f32x4 tb = mfma16(rb, idf, Z);
                u32x4 tB = (u32x4){ bf16pk(ta.x, ta.y), bf16pk(ta.z, ta.w),
                                    bf16pk(tb.x, tb.y), bf16pk(tb.z, tb.w) };
                Tacc[jt] = mfma32(pa, tB, Tacc[jt]);
            }
        }
        ls += __shfl_xor(ls, 16); ls += __shfl_xor(ls, 32);
        li[qt] = 1.0f / ls;   // for q = wr0 + 16*qt + h

        // transpose-pack Tacc -> tBO[qt] (frees Tacc before next pass)
#pragma unroll
        for (int c2 = 0; c2 < 4; ++c2) {
            u32x2 p0 = (u32x2){ bf16pk(Tacc[2 * c2].x, Tacc[2 * c2].y),
                                bf16pk(Tacc[2 * c2].z, Tacc[2 * c2].w) };
            u32x2 p1 = (u32x2){ bf16pk(Tacc[2 * c2 + 1].x, Tacc[2 * c2 + 1].y),
                                bf16pk(Tacc[2 * c2 + 1].z, Tacc[2 * c2 + 1].w) };
            f32x4 d0 = mfma16(p0, idf, Z);   // lane: T[q=h][d=32c2+4g+r]
            f32x4 d1 = mfma16(p1, idf, Z);   // lane: T[q=h][d=32c2+16+4g+r]
            tBO[qt][c2] = (u32x4){ bf16pk(d0.x, d0.y), bf16pk(d0.z, d0.w),
                                   bf16pk(d1.x, d1.y), bf16pk(d1.z, d1.w) };
        }
    }
    __syncthreads();   // all Xs reads done; [0,32K) reusable

    // -- stage Wv into LDS[0,32K) (fp32 -> bf16, swizzled) --
    {
        const int j  = t >> 2;
        const int d0 = (t & 3) << 5;
        const float* src = Wv + j * 128 + d0;
#pragma unroll
        for (int m2 = 0; m2 < 4; ++m2) {
            f32x4 a = *(const f32x4*)(src + 8 * m2);
            f32x4 b = *(const f32x4*)(src + 8 * m2 + 4);
            u32x4 p = (u32x4){ bf16pk(a.x, a.y), bf16pk(a.z, a.w),
                               bf16pk(b.x, b.y), bf16pk(b.z, b.w) };
            *(u32x4*)(sm + wf4_off(j, d0 + 8 * m2)) = p;
        }
    }
    __syncthreads();

    // -- O^T = Wv * T^T ; normalize + bias ; f32x4 stores --
#pragma unroll
    for (int ot = 0; ot < 8; ++ot) {
        f32x4 o0 = Z, o1 = Z;
#pragma unroll
        for (int c2 = 0; c2 < 4; ++c2) {
            u32x2 wlo = *(const u32x2*)(sm + wf4_off(h + 16 * ot, 32 * c2 + 4 * g));
            u32x2 whi = *(const u32x2*)(sm + wf4_off(h + 16 * ot, 32 * c2 + 16 + 4 * g));
            u32x4 A = (u32x4){ wlo.x, wlo.y, whi.x, whi.y };
            o0 = mfma32(A, tBO[0][c2], o0);
            o1 = mfma32(A, tBO[1][c2], o1);
        }
        f32x4 bvv = *(const f32x4*)(bv + 16 * ot + 4 * g);
        f32x4 r0v, r1v;
#pragma unroll
        for (int r = 0; r < 4; ++r) {
            r0v[r] = o0[r] * li[0] + bvv[r];
            r1v[r] = o1[r] * li[1] + bvv[r];
        }
        *(f32x4*)(out + (size_t)(R0 + wr0 + h) * 128 + 16 * ot + 4 * g)      = r0v;
        *(f32x4*)(out + (size_t)(R0 + wr0 + 16 + h) * 128 + 16 * ot + 4 * g) = r1v;
    }
}

extern "C" void kernel_launch(void* const* d_in, const int* in_sizes, int n_in,
                              void* d_out, int out_size, void* d_ws, size_t ws_size,
                              hipStream_t stream) {
    const float* x  = (const float*)d_in[0];
    const float* Wq = (const float*)d_in[2];
    const float* bq = (const float*)d_in[3];
    const float* Wk = (const float*)d_in[4];
    const float* Wv = (const float*)d_in[6];
    const float* bv = (const float*)d_in[7];
    float* out = (float*)d_out;
    char* wsb = (char*)d_ws;

    hipFuncSetAttribute((const void*)sattn,
                        hipFuncAttributeMaxDynamicSharedMemorySize, LDSSZ);

    sattn_pre<<<dim3(65), dim3(256), 0, stream>>>(Wq, bq, Wk, wsb);
    sattn<<<dim3(512), dim3(512), LDSSZ, stream>>>(x, Wv, bv, wsb, out);
}